// Round 14
// baseline (470.107 us; speedup 1.0000x reference)
//
#include <hip/hip_runtime.h>
#include <hip/hip_bf16.h>

#define B_ 32
#define N_ 900
#define BN 8
#define NTILES 113
#define MS 16
#define MP 960   // m/n padded to 15*64

typedef __attribute__((ext_vector_type(8))) short bf16x8;
typedef __attribute__((ext_vector_type(16))) float f32x16;

// ---- workspace layout (bytes) ----
#define OFF_XT 0u                 // xT bf16 [32][384][960]   = 23,592,960
#define OFF_CT 23592960u          // chebT bf16 [2][960][960] =  3,686,400
#define OFF_XC 27279360u          // xcb bf16 [2][32][960][384] NATURAL c=f*24+t = 47,185,920
#define OFF_TH 74465280u          // thT bf16 [64][56]  = 7,168
#define OFF_TW 74472448u          // twB bf16 [64][216] = 27,648
#define WS_NEED 74500096u

// ============================================================
// K0a: xT[b][c][m] = bf16(x[b][m][c]), m zero-padded to 960
// ============================================================
__global__ __launch_bounds__(256)
void k0a_xT(const float* __restrict__ x, __hip_bfloat16* __restrict__ xT)
{
    __shared__ __hip_bfloat16 L[32][390];
    const int tid = threadIdx.x;
    const int m0 = blockIdx.x * 32, b = blockIdx.y;
#pragma unroll
    for (int it = 0; it < 12; ++it) {
        const int idx = tid + it * 256;
        const int mm = idx / 96, c4 = idx - mm * 96;
        float4 v = make_float4(0.f, 0.f, 0.f, 0.f);
        if (m0 + mm < N_)
            v = ((const float4*)(x + ((size_t)b * N_ + m0 + mm) * 384))[c4];
        L[mm][c4 * 4 + 0] = __float2bfloat16(v.x);
        L[mm][c4 * 4 + 1] = __float2bfloat16(v.y);
        L[mm][c4 * 4 + 2] = __float2bfloat16(v.z);
        L[mm][c4 * 4 + 3] = __float2bfloat16(v.w);
    }
    __syncthreads();
#pragma unroll
    for (int it = 0; it < 48; ++it) {
        const int idx = tid + it * 256;
        const int c = idx >> 5, mm = idx & 31;
        xT[((size_t)b * 384 + c) * MP + m0 + mm] = L[mm][c];
    }
}

// ============================================================
// K0b: chebT[k][n][m] = bf16(cheb[k+1][m][n]), zero-padded to 960x960
// ============================================================
__global__ __launch_bounds__(256)
void k0b_chebT(const float* __restrict__ cheb, __hip_bfloat16* __restrict__ chebT)
{
    __shared__ float L[32][33];
    const int tid = threadIdx.x;
    const int m0 = blockIdx.x * 32, n0 = blockIdx.y * 32, k = blockIdx.z;
#pragma unroll
    for (int it = 0; it < 4; ++it) {
        const int idx = tid + it * 256;
        const int mm = idx >> 5, nn = idx & 31;
        float v = 0.f;
        if (m0 + mm < N_ && n0 + nn < N_)
            v = cheb[(size_t)(k + 1) * (N_ * N_) + (size_t)(m0 + mm) * N_ + n0 + nn];
        L[mm][nn] = v;
    }
    __syncthreads();
#pragma unroll
    for (int it = 0; it < 4; ++it) {
        const int idx = tid + it * 256;
        const int nn = idx >> 5, mm = idx & 31;
        chebT[((size_t)k * MP + n0 + nn) * MP + m0 + mm] = __float2bfloat16(L[mm][nn]);
    }
}

// ============================================================
// K0c: thT[c][k] bf16 (pad 56); twB[co][k] bf16 (k<192 conv, 192..207 rw, pad 216)
// ============================================================
__global__ __launch_bounds__(256)
void k0c_w(const float* __restrict__ tw, const float* __restrict__ rw,
           const float* __restrict__ th,
           __hip_bfloat16* __restrict__ thT, __hip_bfloat16* __restrict__ twB)
{
    const int tid = threadIdx.x;
    for (int i = tid; i < 64 * 56; i += 256) {
        const int c = i / 56, k = i - (i / 56) * 56;
        const float v = (k < 48) ? th[k * 64 + c] : 0.f;
        thT[i] = __float2bfloat16(v);
    }
    for (int i = tid; i < 64 * 216; i += 256) {
        const int co = i / 216, k = i - co * 216;
        float v = 0.f;
        if (k < 192)      v = tw[co * 192 + (k & 63) * 3 + (k >> 6)];
        else if (k < 208) v = rw[co * 16 + (k - 192)];
        twB[i] = __float2bfloat16(v);
    }
}

// ============================================================
// K1: MFMA GEMM, 192x128 tile (8 waves, 3 sub-tiles/wave), K-step 32,
// dbuf LDS 51,200 B. Natural store xcb[k][b][n][c]. XCD-chunked swizzle.
// (unchanged from rounds 12/13)
// ============================================================
__global__ __launch_bounds__(512)
void k1_mfma(const __hip_bfloat16* __restrict__ xT,
             const __hip_bfloat16* __restrict__ chebT,
             __hip_bfloat16* __restrict__ xcb)
{
    __shared__ __align__(16) __hip_bfloat16 At[2][192][40];
    __shared__ __align__(16) __hip_bfloat16 Bt[2][128][40];
    const int tid = threadIdx.x;
    const int id  = blockIdx.x;
    const int swz  = (id & 7) * 120 + (id >> 3);
    const int tile = swz % 15;
    const int z    = swz / 15;
    const int n0 = (tile % 5) * 192;
    const int c0 = (tile / 5) * 128;
    const int b = z >> 1, k = z & 1;

    const int wid = tid >> 6, lane = tid & 63;
    const int wr = wid & 1, wc = wid >> 1;
    const int lr = lane & 31, hi = lane >> 5;

    const __hip_bfloat16* Asrc = chebT + ((size_t)k * MP + n0) * MP;
    const __hip_bfloat16* Bsrc = xT + ((size_t)b * 384 + c0) * MP;

    f32x16 acc[3];
#pragma unroll
    for (int rb = 0; rb < 3; ++rb)
#pragma unroll
        for (int j = 0; j < 16; ++j) acc[rb][j] = 0.f;

    auto stage = [&](int buf, int m0) {
        for (int q = tid; q < 768; q += 512) {
            const int r = q >> 2, c8 = (q & 3) * 8;
            *(int4*)&At[buf][r][c8] = *(const int4*)(Asrc + (size_t)r * MP + m0 + c8);
        }
        {
            const int q = tid;
            if (q < 512) {
                const int r = q >> 2, c8 = (q & 3) * 8;
                *(int4*)&Bt[buf][r][c8] = *(const int4*)(Bsrc + (size_t)r * MP + m0 + c8);
            }
        }
    };

    stage(0, 0);
    __syncthreads();
    for (int s = 0; s < 30; ++s) {
        if (s + 1 < 30) stage((s + 1) & 1, (s + 1) * 32);
        const int cur = s & 1;
#pragma unroll
        for (int ks = 0; ks < 2; ++ks) {
            const bf16x8 bb = *(const bf16x8*)&Bt[cur][wc * 32 + lr][ks * 16 + hi * 8];
#pragma unroll
            for (int rb = 0; rb < 3; ++rb) {
                const bf16x8 a =
                    *(const bf16x8*)&At[cur][wr * 96 + rb * 32 + lr][ks * 16 + hi * 8];
                acc[rb] = __builtin_amdgcn_mfma_f32_32x32x16_bf16(a, bb, acc[rb], 0, 0, 0);
            }
        }
        __syncthreads();
    }

    const int c = c0 + wc * 32 + lr;
    __hip_bfloat16* ob = xcb + ((size_t)(k * B_ + b)) * (MP * 384) + c;
#pragma unroll
    for (int rb = 0; rb < 3; ++rb)
#pragma unroll
        for (int reg = 0; reg < 16; ++reg) {
            const int row = n0 + wr * 96 + rb * 32 + (reg & 3) + 8 * (reg >> 2) + 4 * hi;
            ob[(size_t)row * 384] = __float2bfloat16(acc[rb][reg]);
        }
}

// ============================================================
// K2 (full MFMA, multi-job pipelined): each block runs 4 n-tile jobs;
// job j+1's global loads issue before job j's compute (T14 async-STAGE),
// LDS write deferred past phase-B MFMAs. 2 barriers/job, single-buffered
// LDS (frag-extract makes xcL/xbL dead before overwrite; gcn pads persist).
// LDS 52,224 B -> 3 blocks/CU.
// ============================================================
__global__ __launch_bounds__(384, 5)
void k2_mfma(const float* __restrict__ x,
             const __hip_bfloat16* __restrict__ xcb,
             const __hip_bfloat16* __restrict__ thT,
             const __hip_bfloat16* __restrict__ twB,
             const float* __restrict__ tb, const float* __restrict__ rb,
             const float* __restrict__ gam, const float* __restrict__ bet,
             float* __restrict__ out)
{
    __shared__ __align__(16) short xcL[2][8][384];             // 12288 B natural [kk][nl][c]
    __shared__ __align__(16) __hip_bfloat16 xbL[8][24][24];    //  9216 B [nl][t][f]
    __shared__ __align__(16) __hip_bfloat16 gcnL[8][26][72];   // 29952 B
    __shared__ float biasL[64], gamL[64], betL[64];            //   768 B

    const int tid = threadIdx.x;
    const int wid = tid >> 6, lane = tid & 63;
    const int l31 = lane & 31, hi = lane >> 5;
    const int b = blockIdx.y;
    const int tile0 = blockIdx.x * 4;

    if (tid < 64) {
        biasL[tid] = tb[tid] + rb[tid];
        gamL[tid]  = gam[tid];
        betL[tid]  = bet[tid];
    }
    for (int i = tid; i < 1024; i += 384) {   // gcn t-pad rows: persist across jobs
        const int nl = i >> 7, c = (i >> 1) & 63, e = i & 1;
        gcnL[nl][e ? 25 : 0][c] = __float2bfloat16(0.f);
    }

    // per-thread staging: 2 int4 (xc) + 2 float4 (x) held in regs
    int4   rxc[2];
    float4 rx[2];
    auto ldregs = [&](int tile) {
        const int nb = tile * BN;   // tiles up to 115: nb+nl <= 927 < MP, in-bounds
#pragma unroll
        for (int u = 0; u < 2; ++u) {
            const int q = tid + u * 384;
            const int kk = q / 384, r = q - kk * 384;
            const int nl = r / 48, ch = r - nl * 48;
            rxc[u] = *(const int4*)(xcb + (((size_t)(kk * B_ + b)) * MP + nb + nl) * 384 + ch * 8);
        }
#pragma unroll
        for (int u = 0; u < 2; ++u) {
            const int i = tid + u * 384;
            const int nl = i / 96, rem = i - nl * 96, f = rem / 6, t4 = rem - f * 6;
            const int ng = nb + nl;
            rx[u] = (ng < N_)
                ? ((const float4*)(x + ((size_t)b * N_ + ng) * 384 + f * 24))[t4]
                : make_float4(0.f, 0.f, 0.f, 0.f);
        }
    };
    auto dswrite = [&]() {
#pragma unroll
        for (int u = 0; u < 2; ++u) ((int4*)xcL)[tid + u * 384] = rxc[u];
#pragma unroll
        for (int u = 0; u < 2; ++u) {
            const int i = tid + u * 384;
            const int nl = i / 96, rem = i - nl * 96, f = rem / 6, t4 = rem - f * 6;
            xbL[nl][t4 * 4 + 0][f] = __float2bfloat16(rx[u].x);
            xbL[nl][t4 * 4 + 1][f] = __float2bfloat16(rx[u].y);
            xbL[nl][t4 * 4 + 2][f] = __float2bfloat16(rx[u].z);
            xbL[nl][t4 * 4 + 3][f] = __float2bfloat16(rx[u].w);
        }
    };

    const int colA = wid * 32 + l31;            // 0..191
    const int nlA = colA / 24, tA = colA - nlA * 24;

    ldregs(tile0);
    dswrite();
    __syncthreads();   // β0

    for (int j = 0; j < 4; ++j) {
        const int tile = tile0 + j;

        // extract B-fragments (xcL/xbL last read)
        const bf16x8 b0 = *(const bf16x8*)&xbL[nlA][tA][hi * 8];
        bf16x8 b1, b2;
#pragma unroll
        for (int jj = 0; jj < 8; ++jj) {
            b1[jj] = xcL[0][nlA][(hi * 8 + jj) * 24 + tA];
            b2[jj] = xcL[1][nlA][(hi * 8 + jj) * 24 + tA];
        }
        if (j < 3) ldregs(tile + 1);   // issue next-job loads; latency hides under A+B

        // ---- phase A: theta GEMM (A-frags direct from global thT) -> gcnL ----
        {
            const short* thg = (const short*)thT;
            f32x16 a0, a1;
#pragma unroll
            for (int jj = 0; jj < 16; ++jj) { a0[jj] = 0.f; a1[jj] = 0.f; }
            bf16x8 af;
            af = *(const bf16x8*)(thg + l31 * 56 + hi * 8);
            a0 = __builtin_amdgcn_mfma_f32_32x32x16_bf16(af, b0, a0, 0, 0, 0);
            af = *(const bf16x8*)(thg + l31 * 56 + 16 + hi * 8);
            a0 = __builtin_amdgcn_mfma_f32_32x32x16_bf16(af, b1, a0, 0, 0, 0);
            af = *(const bf16x8*)(thg + l31 * 56 + 32 + hi * 8);
            a0 = __builtin_amdgcn_mfma_f32_32x32x16_bf16(af, b2, a0, 0, 0, 0);
            af = *(const bf16x8*)(thg + (32 + l31) * 56 + hi * 8);
            a1 = __builtin_amdgcn_mfma_f32_32x32x16_bf16(af, b0, a1, 0, 0, 0);
            af = *(const bf16x8*)(thg + (32 + l31) * 56 + 16 + hi * 8);
            a1 = __builtin_amdgcn_mfma_f32_32x32x16_bf16(af, b1, a1, 0, 0, 0);
            af = *(const bf16x8*)(thg + (32 + l31) * 56 + 32 + hi * 8);
            a1 = __builtin_amdgcn_mfma_f32_32x32x16_bf16(af, b2, a1, 0, 0, 0);
#pragma unroll
            for (int reg = 0; reg < 16; ++reg) {
                const int cr = (reg & 3) + 8 * (reg >> 2) + 4 * hi;
                gcnL[nlA][tA + 1][cr]      = __float2bfloat16(fmaxf(a0[reg], 0.f));
                gcnL[nlA][tA + 1][32 + cr] = __float2bfloat16(fmaxf(a1[reg], 0.f));
            }
        }
        __syncthreads();   // β1: all frags extracted + gcnL(j) ready

        // ---- phase B: [tw|rw] GEMM; A-frags direct from global twB ----
        const short* twg = (const short*)twB;
        f32x16 acc0, acc1;
#pragma unroll
        for (int jj = 0; jj < 16; ++jj) { acc0[jj] = 0.f; acc1[jj] = 0.f; }
#pragma unroll
        for (int s = 0; s < 12; ++s) {
            const int dt  = s >> 2;
            const int ci0 = (s & 3) * 16 + hi * 8;
            const bf16x8 bb = *(const bf16x8*)&gcnL[nlA][tA + dt][ci0];
            const bf16x8 a0 = *(const bf16x8*)(twg + l31 * 216 + dt * 64 + ci0);
            const bf16x8 a1 = *(const bf16x8*)(twg + (32 + l31) * 216 + dt * 64 + ci0);
            acc0 = __builtin_amdgcn_mfma_f32_32x32x16_bf16(a0, bb, acc0, 0, 0, 0);
            acc1 = __builtin_amdgcn_mfma_f32_32x32x16_bf16(a1, bb, acc1, 0, 0, 0);
        }
        {   // residual K-step (k=192..207 -> f), B = b0 (x fragment)
            const bf16x8 a0 = *(const bf16x8*)(twg + l31 * 216 + 192 + hi * 8);
            const bf16x8 a1 = *(const bf16x8*)(twg + (32 + l31) * 216 + 192 + hi * 8);
            acc0 = __builtin_amdgcn_mfma_f32_32x32x16_bf16(a0, b0, acc0, 0, 0, 0);
            acc1 = __builtin_amdgcn_mfma_f32_32x32x16_bf16(a1, b0, acc1, 0, 0, 0);
        }

        // deferred LDS write for job j+1 (touches xcL/xbL only; B reads gcnL)
        if (j < 3) dswrite();

        // ---- epilogue: bias + relu + LN(co) + store (B,N,F,T) f32 ----
        float y0[16], y1[16];
        float s1 = 0.f, s2 = 0.f;
#pragma unroll
        for (int reg = 0; reg < 16; ++reg) {
            const int cr = (reg & 3) + 8 * (reg >> 2) + 4 * hi;
            const float v0 = fmaxf(acc0[reg] + biasL[cr], 0.f);
            const float v1 = fmaxf(acc1[reg] + biasL[32 + cr], 0.f);
            y0[reg] = v0; y1[reg] = v1;
            s1 += v0 + v1;
            s2 += v0 * v0 + v1 * v1;
        }
        s1 += __shfl_xor(s1, 32);
        s2 += __shfl_xor(s2, 32);
        const float mu  = s1 * (1.f / 64.f);
        const float var = fmaxf(s2 * (1.f / 64.f) - mu * mu, 0.f);
        const float rs  = rsqrtf(var + 1e-5f);

        const int ng = tile * BN + nlA;
        if (ng < N_) {
            float* op = out + ((size_t)b * N_ + ng) * 1536 + tA;
#pragma unroll
            for (int reg = 0; reg < 16; ++reg) {
                const int cr = (reg & 3) + 8 * (reg >> 2) + 4 * hi;
                op[(size_t)cr * 24]        = (y0[reg] - mu) * rs * gamL[cr] + betL[cr];
                op[(size_t)(32 + cr) * 24] = (y1[reg] - mu) * rs * gamL[32 + cr] + betL[32 + cr];
            }
        }
        __syncthreads();   // β2: xcL/xbL(j+1) written; gcnL reads complete
    }
}

// ============================================================
// Fallback: validated round-7 fused kernel (ws too small)
// ============================================================
__global__ __launch_bounds__(256, 2)
void astgcn_fused(const float* __restrict__ x, const float* __restrict__ cheb,
                  const float* __restrict__ theta, const float* __restrict__ tw,
                  const float* __restrict__ tb, const float* __restrict__ rw,
                  const float* __restrict__ rb, const float* __restrict__ gam,
                  const float* __restrict__ bet, float* __restrict__ out)
{
    __shared__ __align__(16) unsigned char smem[57152];
    float* xc   = (float*)smem;
    unsigned char* Y = smem + 24576;
    float* rwl  = (float*)(smem + 52032);
    float* misc = (float*)(smem + 56128);

    const int tid = threadIdx.x;
    const int n_base = blockIdx.x * BN;
    const int b = blockIdx.y;

    if (tid < 64) {
        misc[tid]       = tb[tid];
        misc[64 + tid]  = rb[tid];
        misc[128 + tid] = gam[tid];
        misc[192 + tid] = bet[tid];
    }
    for (int i = tid; i < 1024; i += 256) {
        const int co = i & 63, f = i >> 6;
        rwl[f * 64 + co] = rw[co * 16 + f];
    }

    float* xs  = (float*)Y;
    float* wls = (float*)(Y + 24576);
    const int nloc = tid >> 5;
    const int cg   = tid & 31;
    float a1[12], a2[12];
#pragma unroll
    for (int j = 0; j < 12; ++j) { a1[j] = 0.f; a2[j] = 0.f; }
    const float* xb = x + (size_t)b * N_ * 384;

    for (int mc = 0; mc < N_; mc += MS) {
        const int mlim = (N_ - mc) < MS ? (N_ - mc) : MS;
        __syncthreads();
        for (int i = tid; i < mlim * 96; i += 256) {
            const int mm = i / 96, c4 = i - mm * 96;
            ((float4*)(xs + mm * 384))[c4] =
                ((const float4*)(xb + (size_t)(mc + mm) * 384))[c4];
        }
        for (int i = tid; i < 2 * MS * 8; i += 256) {
            const int k = i >> 7, mm = (i >> 3) & 15, nn = i & 7;
            const int ng = n_base + nn;
            float wv = 0.f;
            if (mm < mlim && ng < N_)
                wv = cheb[(size_t)(k + 1) * (N_ * N_) + (size_t)(mc + mm) * N_ + ng];
            wls[(k * MS + mm) * 8 + nn] = wv;
        }
        __syncthreads();
        for (int mm = 0; mm < mlim; ++mm) {
            const float w1 = wls[mm * 8 + nloc];
            const float w2 = wls[(MS + mm) * 8 + nloc];
            const float* xr = xs + mm * 384 + (cg << 2);
#pragma unroll
            for (int seg = 0; seg < 3; ++seg) {
                const float4 v = *(const float4*)(xr + seg * 128);
                a1[seg*4+0] = fmaf(w1, v.x, a1[seg*4+0]);
                a1[seg*4+1] = fmaf(w1, v.y, a1[seg*4+1]);
                a1[seg*4+2] = fmaf(w1, v.z, a1[seg*4+2]);
                a1[seg*4+3] = fmaf(w1, v.w, a1[seg*4+3]);
                a2[seg*4+0] = fmaf(w2, v.x, a2[seg*4+0]);
                a2[seg*4+1] = fmaf(w2, v.y, a2[seg*4+1]);
                a2[seg*4+2] = fmaf(w2, v.z, a2[seg*4+2]);
                a2[seg*4+3] = fmaf(w2, v.w, a2[seg*4+3]);
            }
        }
    }
    __syncthreads();
#pragma unroll
    for (int seg = 0; seg < 3; ++seg) {
#pragma unroll
        for (int jj = 0; jj < 4; ++jj) {
            const int c = seg * 128 + (cg << 2) + jj;
            const int f = c / 24, t = c - f * 24;
            xc[(nloc * 24 + t) * 16 + f]        = a1[seg * 4 + jj];
            xc[((BN + nloc) * 24 + t) * 16 + f] = a2[seg * 4 + jj];
        }
    }
    __syncthreads();

    __hip_bfloat16* gcn = (__hip_bfloat16*)Y;
    {
        const int c2 = tid & 63;
        const int pg = tid >> 6;
        float th0r[16], th1r[16], th2r[16];
#pragma unroll
        for (int f = 0; f < 16; ++f) {
            th0r[f] = theta[f * 64 + c2];
            th1r[f] = theta[(16 + f) * 64 + c2];
            th2r[f] = theta[(32 + f) * 64 + c2];
        }
        for (int i = 0; i < 48; ++i) {
            const int p  = pg + 4 * i;
            const int nl = p / 24, t = p - nl * 24;
            const int ng = n_base + nl;
            float o = 0.f;
            if (ng < N_) {
                const float* xg = x + ((size_t)b * N_ + ng) * 384 + t;
                const float* x1 = xc + (nl * 24 + t) * 16;
                const float* x2 = xc + ((BN + nl) * 24 + t) * 16;
#pragma unroll
                for (int f = 0; f < 16; ++f)
                    o = fmaf(xg[f * 24], th0r[f], o);
#pragma unroll
                for (int f = 0; f < 16; ++f)
                    o = fmaf(x1[f], th1r[f], fmaf(x2[f], th2r[f], o));
            }
            o = fmaxf(o, 0.f);
            gcn[(nl * 26 + t + 1) * 66 + c2] = __float2bfloat16(o);
            if (t == 0)  gcn[(nl * 26) * 66 + c2]      = __float2bfloat16(0.f);
            if (t == 23) gcn[(nl * 26 + 25) * 66 + c2] = __float2bfloat16(0.f);
        }
    }

    const int nl3 = tid / 24, t3 = tid - nl3 * 24;
    const int ng3 = n_base + nl3;
    const bool act = (tid < 192) && (ng3 < N_);
    float acc[64];
#pragma unroll
    for (int co = 0; co < 64; ++co) acc[co] = misc[co] + misc[64 + co];
    if (act) {
        const float* xg = x + ((size_t)b * N_ + ng3) * 384 + t3;
#pragma unroll
        for (int f = 0; f < 16; ++f) {
            const float xv = xg[f * 24];
            const float* rp = rwl + f * 64;
#pragma unroll
            for (int co = 0; co < 64; ++co) acc[co] = fmaf(xv, rp[co], acc[co]);
        }
    }
    float* twl = xc;
#pragma unroll
    for (int half = 0; half < 2; ++half) {
        __syncthreads();
        for (int i = tid; i < 6144; i += 256)
            twl[i] = tw[((half * 32) + (i & 31)) * 192 + ((i >> 5) & 63) * 3 + (i >> 11)];
        __syncthreads();
        if (act) {
            const __hip_bfloat16* g0 = gcn + (nl3 * 26 + t3) * 66;
#pragma unroll
            for (int dt = 0; dt < 3; ++dt) {
                const __hip_bfloat16* grow = g0 + dt * 66;
                for (int ci = 0; ci < 64; ++ci) {
                    const float g = __bfloat162float(grow[ci]);
                    const float* twp = twl + (dt * 64 + ci) * 32;
#pragma unroll
                    for (int j = 0; j < 32; ++j)
                        acc[half * 32 + j] = fmaf(g, twp[j], acc[half * 32 + j]);
                }
            }
        }
    }
    if (act) {
        float mu = 0.f;
#pragma unroll
        for (int co = 0; co < 64; ++co) { acc[co] = fmaxf(acc[co], 0.f); mu += acc[co]; }
        mu *= (1.f / 64.f);
        float var = 0.f;
#pragma unroll
        for (int co = 0; co < 64; ++co) { const float d = acc[co] - mu; var = fmaf(d, d, var); }
        var *= (1.f / 64.f);
        const float rs = rsqrtf(var + 1e-5f);
        float* op = out + ((size_t)b * N_ + ng3) * (64 * 24) + t3;
#pragma unroll
        for (int co = 0; co < 64; ++co) {
            const float yl = (acc[co] - mu) * rs * misc[128 + co] + misc[192 + co];
            op[(size_t)co * 24] = yl;
        }
    }
}

extern "C" void kernel_launch(void* const* d_in, const int* in_sizes, int n_in,
                              void* d_out, int out_size, void* d_ws, size_t ws_size,
                              hipStream_t stream) {
    (void)out_size;
    const float *px = nullptr, *pcheb = nullptr, *pth = nullptr,
                *ptw = nullptr, *prw = nullptr;
    const float* p64[4] = {nullptr, nullptr, nullptr, nullptr};
    int n64 = 0;
    for (int i = 0; i < n_in; ++i) {
        const float* p = (const float*)d_in[i];
        switch (in_sizes[i]) {
            case 11059200: px    = p; break;
            case 2430000:  pcheb = p; break;
            case 3072:     pth   = p; break;
            case 12288:    ptw   = p; break;
            case 1024:     prw   = p; break;
            case 64:       if (n64 < 4) p64[n64] = p; ++n64; break;
            default: break;
        }
    }
    if (!px || !pcheb || !pth || !ptw || !prw || n64 != 4) {
        px    = (const float*)d_in[0]; pcheb = (const float*)d_in[1];
        pth   = (const float*)d_in[2]; ptw   = (const float*)d_in[3];
        p64[0] = (const float*)d_in[4]; prw  = (const float*)d_in[5];
        p64[1] = (const float*)d_in[6]; p64[2] = (const float*)d_in[7];
        p64[3] = (const float*)d_in[8];
    }
    float* out = (float*)d_out;

    if (ws_size >= (size_t)WS_NEED) {
        unsigned char* ws = (unsigned char*)d_ws;
        __hip_bfloat16* xT    = (__hip_bfloat16*)(ws + OFF_XT);
        __hip_bfloat16* chebT = (__hip_bfloat16*)(ws + OFF_CT);
        __hip_bfloat16* xcb   = (__hip_bfloat16*)(ws + OFF_XC);
        __hip_bfloat16* thT   = (__hip_bfloat16*)(ws + OFF_TH);
        __hip_bfloat16* twB   = (__hip_bfloat16*)(ws + OFF_TW);

        k0a_xT   <<<dim3(30, B_),     256, 0, stream>>>(px, xT);
        k0b_chebT<<<dim3(30, 30, 2),  256, 0, stream>>>(pcheb, chebT);
        k0c_w    <<<1,                256, 0, stream>>>(ptw, prw, pth, thT, twB);
        k1_mfma  <<<960,              512, 0, stream>>>(xT, chebT, xcb);
        k2_mfma  <<<dim3(29, B_),     384, 0, stream>>>(px, xcb, thT, twB,
                                                        p64[0], p64[1], p64[2], p64[3], out);
    } else {
        astgcn_fused<<<dim3(NTILES, B_), 256, 0, stream>>>(px, pcheb, pth, ptw,
                                                           p64[0], prw, p64[1],
                                                           p64[2], p64[3], out);
    }
}

// Round 15
// 195.280 us; speedup vs baseline: 2.4073x; 2.4073x over previous
//
#include <hip/hip_runtime.h>
#include <hip/hip_bf16.h>

#define B_ 32
#define N_ 900
#define BN 8
#define NTILES 113
#define MS 16
#define MP 960   // m/n padded to 15*64

typedef __attribute__((ext_vector_type(8))) short bf16x8;
typedef __attribute__((ext_vector_type(16))) float f32x16;

// ---- workspace layout (bytes) ----
#define OFF_XT 0u                 // xT bf16 [32][384][960]   = 23,592,960
#define OFF_CT 23592960u          // chebT bf16 [2][960][960] =  3,686,400
#define OFF_XC 27279360u          // xcb bf16 [2][32][960][384] NATURAL c=f*24+t = 47,185,920
#define OFF_TH 74465280u          // thT bf16 [64][56]  = 7,168
#define OFF_TW 74472448u          // twB bf16 [64][216] = 27,648
#define WS_NEED 74500096u

// ============================================================
// K0 (fused): blocks [0,960) = xT transpose; [960,2760) = chebT transpose;
// block 2760 = weight repack. Bodies identical to the former k0a/k0b/k0c.
// ============================================================
__global__ __launch_bounds__(256)
void k0_all(const float* __restrict__ x, const float* __restrict__ cheb,
            const float* __restrict__ tw, const float* __restrict__ rw,
            const float* __restrict__ th,
            __hip_bfloat16* __restrict__ xT, __hip_bfloat16* __restrict__ chebT,
            __hip_bfloat16* __restrict__ thT, __hip_bfloat16* __restrict__ twB)
{
    __shared__ __align__(16) unsigned char sm[24960];
    const int bid = blockIdx.x;
    const int tid = threadIdx.x;

    if (bid < 960) {
        // ---- xT[b][c][m] = bf16(x[b][m][c]), m zero-padded to 960 ----
        __hip_bfloat16 (*L)[390] = (__hip_bfloat16(*)[390])sm;
        const int m0 = (bid % 30) * 32, b = bid / 30;
#pragma unroll
        for (int it = 0; it < 12; ++it) {
            const int idx = tid + it * 256;
            const int mm = idx / 96, c4 = idx - mm * 96;
            float4 v = make_float4(0.f, 0.f, 0.f, 0.f);
            if (m0 + mm < N_)
                v = ((const float4*)(x + ((size_t)b * N_ + m0 + mm) * 384))[c4];
            L[mm][c4 * 4 + 0] = __float2bfloat16(v.x);
            L[mm][c4 * 4 + 1] = __float2bfloat16(v.y);
            L[mm][c4 * 4 + 2] = __float2bfloat16(v.z);
            L[mm][c4 * 4 + 3] = __float2bfloat16(v.w);
        }
        __syncthreads();
#pragma unroll
        for (int it = 0; it < 48; ++it) {
            const int idx = tid + it * 256;
            const int c = idx >> 5, mm = idx & 31;
            xT[((size_t)b * 384 + c) * MP + m0 + mm] = L[mm][c];
        }
    } else if (bid < 2760) {
        // ---- chebT[k][n][m] = bf16(cheb[k+1][m][n]), padded 960x960 ----
        float (*L)[33] = (float(*)[33])sm;
        const int r = bid - 960;
        const int m0 = (r % 30) * 32, n0 = ((r / 30) % 30) * 32, k = r / 900;
#pragma unroll
        for (int it = 0; it < 4; ++it) {
            const int idx = tid + it * 256;
            const int mm = idx >> 5, nn = idx & 31;
            float v = 0.f;
            if (m0 + mm < N_ && n0 + nn < N_)
                v = cheb[(size_t)(k + 1) * (N_ * N_) + (size_t)(m0 + mm) * N_ + n0 + nn];
            L[mm][nn] = v;
        }
        __syncthreads();
#pragma unroll
        for (int it = 0; it < 4; ++it) {
            const int idx = tid + it * 256;
            const int nn = idx >> 5, mm = idx & 31;
            chebT[((size_t)k * MP + n0 + nn) * MP + m0 + mm] = __float2bfloat16(L[mm][nn]);
        }
    } else {
        // ---- thT[c][k] (pad 56); twB[co][k] (k<192 conv, 192..207 rw, pad 216) ----
        for (int i = tid; i < 64 * 56; i += 256) {
            const int c = i / 56, k = i - (i / 56) * 56;
            const float v = (k < 48) ? th[k * 64 + c] : 0.f;
            thT[i] = __float2bfloat16(v);
        }
        for (int i = tid; i < 64 * 216; i += 256) {
            const int co = i / 216, k = i - co * 216;
            float v = 0.f;
            if (k < 192)      v = tw[co * 192 + (k & 63) * 3 + (k >> 6)];
            else if (k < 208) v = rw[co * 16 + (k - 192)];
            twB[i] = __float2bfloat16(v);
        }
    }
}

// ============================================================
// K1: MFMA GEMM, 192x128 tile (8 waves, 3 sub-tiles/wave), K-step 32,
// dbuf LDS 51,200 B. Natural store xcb[k][b][n][c]. XCD-chunked swizzle.
// (unchanged from rounds 12/13)
// ============================================================
__global__ __launch_bounds__(512)
void k1_mfma(const __hip_bfloat16* __restrict__ xT,
             const __hip_bfloat16* __restrict__ chebT,
             __hip_bfloat16* __restrict__ xcb)
{
    __shared__ __align__(16) __hip_bfloat16 At[2][192][40];
    __shared__ __align__(16) __hip_bfloat16 Bt[2][128][40];
    const int tid = threadIdx.x;
    const int id  = blockIdx.x;
    const int swz  = (id & 7) * 120 + (id >> 3);
    const int tile = swz % 15;
    const int z    = swz / 15;
    const int n0 = (tile % 5) * 192;
    const int c0 = (tile / 5) * 128;
    const int b = z >> 1, k = z & 1;

    const int wid = tid >> 6, lane = tid & 63;
    const int wr = wid & 1, wc = wid >> 1;
    const int lr = lane & 31, hi = lane >> 5;

    const __hip_bfloat16* Asrc = chebT + ((size_t)k * MP + n0) * MP;
    const __hip_bfloat16* Bsrc = xT + ((size_t)b * 384 + c0) * MP;

    f32x16 acc[3];
#pragma unroll
    for (int rb = 0; rb < 3; ++rb)
#pragma unroll
        for (int j = 0; j < 16; ++j) acc[rb][j] = 0.f;

    auto stage = [&](int buf, int m0) {
        for (int q = tid; q < 768; q += 512) {
            const int r = q >> 2, c8 = (q & 3) * 8;
            *(int4*)&At[buf][r][c8] = *(const int4*)(Asrc + (size_t)r * MP + m0 + c8);
        }
        {
            const int q = tid;
            if (q < 512) {
                const int r = q >> 2, c8 = (q & 3) * 8;
                *(int4*)&Bt[buf][r][c8] = *(const int4*)(Bsrc + (size_t)r * MP + m0 + c8);
            }
        }
    };

    stage(0, 0);
    __syncthreads();
    for (int s = 0; s < 30; ++s) {
        if (s + 1 < 30) stage((s + 1) & 1, (s + 1) * 32);
        const int cur = s & 1;
#pragma unroll
        for (int ks = 0; ks < 2; ++ks) {
            const bf16x8 bb = *(const bf16x8*)&Bt[cur][wc * 32 + lr][ks * 16 + hi * 8];
#pragma unroll
            for (int rb = 0; rb < 3; ++rb) {
                const bf16x8 a =
                    *(const bf16x8*)&At[cur][wr * 96 + rb * 32 + lr][ks * 16 + hi * 8];
                acc[rb] = __builtin_amdgcn_mfma_f32_32x32x16_bf16(a, bb, acc[rb], 0, 0, 0);
            }
        }
        __syncthreads();
    }

    const int c = c0 + wc * 32 + lr;
    __hip_bfloat16* ob = xcb + ((size_t)(k * B_ + b)) * (MP * 384) + c;
#pragma unroll
    for (int rb = 0; rb < 3; ++rb)
#pragma unroll
        for (int reg = 0; reg < 16; ++reg) {
            const int row = n0 + wr * 96 + rb * 32 + (reg & 3) + 8 * (reg >> 2) + 4 * hi;
            ob[(size_t)row * 384] = __float2bfloat16(acc[rb][reg]);
        }
}

// ============================================================
// K2 (full MFMA) — EXACT round-13 version (best validated).
// No twL in LDS: phase-B A-frags direct from global twB (L1/L2-hot with
// 3616 independent single-job blocks). LDS 52,224 B -> 3 blocks/CU.
// ============================================================
__global__ __launch_bounds__(384, 5)
void k2_mfma(const float* __restrict__ x,
             const __hip_bfloat16* __restrict__ xcb,
             const __hip_bfloat16* __restrict__ thT,
             const __hip_bfloat16* __restrict__ twB,
             const float* __restrict__ tb, const float* __restrict__ rb,
             const float* __restrict__ gam, const float* __restrict__ bet,
             float* __restrict__ out)
{
    __shared__ __align__(16) short xcL[2][8][384];             // 12288 B natural [kk][nl][c]
    __shared__ __align__(16) __hip_bfloat16 xbL[8][24][24];    //  9216 B [nl][t][f]
    __shared__ __align__(16) __hip_bfloat16 gcnL[8][26][72];   // 29952 B
    __shared__ float biasL[64], gamL[64], betL[64];            //   768 B

    const int tid = threadIdx.x;
    const int wid = tid >> 6, lane = tid & 63;
    const int l31 = lane & 31, hi = lane >> 5;
    const int n_base = blockIdx.x * BN;
    const int b = blockIdx.y;

    if (tid < 64) {
        biasL[tid] = tb[tid] + rb[tid];
        gamL[tid]  = gam[tid];
        betL[tid]  = bet[tid];
    }
    for (int q = tid; q < 768; q += 384) {
        const int kk = q / 384, r = q - kk * 384;
        const int nl = r / 48, ch = r - nl * 48;
        ((int4*)xcL)[q] =
            *(const int4*)(xcb + (((size_t)(kk * B_ + b)) * MP + n_base + nl) * 384 + ch * 8);
    }
    for (int i = tid; i < 768; i += 384) {
        const int nl = i / 96, rem = i - nl * 96, f = rem / 6, t4 = rem - f * 6;
        const int ng = n_base + nl;
        float4 v = make_float4(0.f, 0.f, 0.f, 0.f);
        if (ng < N_)
            v = ((const float4*)(x + ((size_t)b * N_ + ng) * 384 + f * 24))[t4];
        xbL[nl][t4 * 4 + 0][f] = __float2bfloat16(v.x);
        xbL[nl][t4 * 4 + 1][f] = __float2bfloat16(v.y);
        xbL[nl][t4 * 4 + 2][f] = __float2bfloat16(v.z);
        xbL[nl][t4 * 4 + 3][f] = __float2bfloat16(v.w);
    }
    for (int i = tid; i < 1024; i += 384) {
        const int nl = i >> 7, c = (i >> 1) & 63, e = i & 1;
        gcnL[nl][e ? 25 : 0][c] = __float2bfloat16(0.f);
    }

    const int colA = wid * 32 + l31;            // 0..191
    const int nlA = colA / 24, tA = colA - nlA * 24;

    __syncthreads();   // B0: staging complete

    const bf16x8 b0 = *(const bf16x8*)&xbL[nlA][tA][hi * 8];
    bf16x8 b1, b2;
#pragma unroll
    for (int j = 0; j < 8; ++j) {
        b1[j] = xcL[0][nlA][(hi * 8 + j) * 24 + tA];
        b2[j] = xcL[1][nlA][(hi * 8 + j) * 24 + tA];
    }

    // ---- phase A: theta GEMM (A-frags direct from global thT) -> gcnL ----
    {
        const short* thg = (const short*)thT;
        f32x16 a0, a1;
#pragma unroll
        for (int j = 0; j < 16; ++j) { a0[j] = 0.f; a1[j] = 0.f; }
        bf16x8 af;
        af = *(const bf16x8*)(thg + l31 * 56 + hi * 8);
        a0 = __builtin_amdgcn_mfma_f32_32x32x16_bf16(af, b0, a0, 0, 0, 0);
        af = *(const bf16x8*)(thg + l31 * 56 + 16 + hi * 8);
        a0 = __builtin_amdgcn_mfma_f32_32x32x16_bf16(af, b1, a0, 0, 0, 0);
        af = *(const bf16x8*)(thg + l31 * 56 + 32 + hi * 8);
        a0 = __builtin_amdgcn_mfma_f32_32x32x16_bf16(af, b2, a0, 0, 0, 0);
        af = *(const bf16x8*)(thg + (32 + l31) * 56 + hi * 8);
        a1 = __builtin_amdgcn_mfma_f32_32x32x16_bf16(af, b0, a1, 0, 0, 0);
        af = *(const bf16x8*)(thg + (32 + l31) * 56 + 16 + hi * 8);
        a1 = __builtin_amdgcn_mfma_f32_32x32x16_bf16(af, b1, a1, 0, 0, 0);
        af = *(const bf16x8*)(thg + (32 + l31) * 56 + 32 + hi * 8);
        a1 = __builtin_amdgcn_mfma_f32_32x32x16_bf16(af, b2, a1, 0, 0, 0);
#pragma unroll
        for (int reg = 0; reg < 16; ++reg) {
            const int cr = (reg & 3) + 8 * (reg >> 2) + 4 * hi;
            gcnL[nlA][tA + 1][cr]      = __float2bfloat16(fmaxf(a0[reg], 0.f));
            gcnL[nlA][tA + 1][32 + cr] = __float2bfloat16(fmaxf(a1[reg], 0.f));
        }
    }
    __syncthreads();   // B1: gcnL ready

    // ---- phase B: [tw|rw] GEMM; A-frags direct from global twB ----
    const short* twg = (const short*)twB;
    f32x16 acc0, acc1;
#pragma unroll
    for (int j = 0; j < 16; ++j) { acc0[j] = 0.f; acc1[j] = 0.f; }
#pragma unroll
    for (int s = 0; s < 12; ++s) {
        const int dt  = s >> 2;
        const int ci0 = (s & 3) * 16 + hi * 8;
        const bf16x8 bb = *(const bf16x8*)&gcnL[nlA][tA + dt][ci0];
        const bf16x8 a0 = *(const bf16x8*)(twg + l31 * 216 + dt * 64 + ci0);
        const bf16x8 a1 = *(const bf16x8*)(twg + (32 + l31) * 216 + dt * 64 + ci0);
        acc0 = __builtin_amdgcn_mfma_f32_32x32x16_bf16(a0, bb, acc0, 0, 0, 0);
        acc1 = __builtin_amdgcn_mfma_f32_32x32x16_bf16(a1, bb, acc1, 0, 0, 0);
    }
    {   // residual K-step (k=192..207 -> f), B = b0 (x fragment)
        const bf16x8 a0 = *(const bf16x8*)(twg + l31 * 216 + 192 + hi * 8);
        const bf16x8 a1 = *(const bf16x8*)(twg + (32 + l31) * 216 + 192 + hi * 8);
        acc0 = __builtin_amdgcn_mfma_f32_32x32x16_bf16(a0, b0, acc0, 0, 0, 0);
        acc1 = __builtin_amdgcn_mfma_f32_32x32x16_bf16(a1, b0, acc1, 0, 0, 0);
    }

    // ---- epilogue: bias + relu + LN(co) + store (B,N,F,T) f32 ----
    float y0[16], y1[16];
    float s1 = 0.f, s2 = 0.f;
#pragma unroll
    for (int reg = 0; reg < 16; ++reg) {
        const int cr = (reg & 3) + 8 * (reg >> 2) + 4 * hi;
        const float v0 = fmaxf(acc0[reg] + biasL[cr], 0.f);
        const float v1 = fmaxf(acc1[reg] + biasL[32 + cr], 0.f);
        y0[reg] = v0; y1[reg] = v1;
        s1 += v0 + v1;
        s2 += v0 * v0 + v1 * v1;
    }
    s1 += __shfl_xor(s1, 32);
    s2 += __shfl_xor(s2, 32);
    const float mu  = s1 * (1.f / 64.f);
    const float var = fmaxf(s2 * (1.f / 64.f) - mu * mu, 0.f);
    const float rs  = rsqrtf(var + 1e-5f);

    const int ng = n_base + nlA;
    if (ng < N_) {
        float* op = out + ((size_t)b * N_ + ng) * 1536 + tA;
#pragma unroll
        for (int reg = 0; reg < 16; ++reg) {
            const int cr = (reg & 3) + 8 * (reg >> 2) + 4 * hi;
            op[(size_t)cr * 24]        = (y0[reg] - mu) * rs * gamL[cr] + betL[cr];
            op[(size_t)(32 + cr) * 24] = (y1[reg] - mu) * rs * gamL[32 + cr] + betL[32 + cr];
        }
    }
}

// ============================================================
// Fallback: validated round-7 fused kernel (ws too small)
// ============================================================
__global__ __launch_bounds__(256, 2)
void astgcn_fused(const float* __restrict__ x, const float* __restrict__ cheb,
                  const float* __restrict__ theta, const float* __restrict__ tw,
                  const float* __restrict__ tb, const float* __restrict__ rw,
                  const float* __restrict__ rb, const float* __restrict__ gam,
                  const float* __restrict__ bet, float* __restrict__ out)
{
    __shared__ __align__(16) unsigned char smem[57152];
    float* xc   = (float*)smem;
    unsigned char* Y = smem + 24576;
    float* rwl  = (float*)(smem + 52032);
    float* misc = (float*)(smem + 56128);

    const int tid = threadIdx.x;
    const int n_base = blockIdx.x * BN;
    const int b = blockIdx.y;

    if (tid < 64) {
        misc[tid]       = tb[tid];
        misc[64 + tid]  = rb[tid];
        misc[128 + tid] = gam[tid];
        misc[192 + tid] = bet[tid];
    }
    for (int i = tid; i < 1024; i += 256) {
        const int co = i & 63, f = i >> 6;
        rwl[f * 64 + co] = rw[co * 16 + f];
    }

    float* xs  = (float*)Y;
    float* wls = (float*)(Y + 24576);
    const int nloc = tid >> 5;
    const int cg   = tid & 31;
    float a1[12], a2[12];
#pragma unroll
    for (int j = 0; j < 12; ++j) { a1[j] = 0.f; a2[j] = 0.f; }
    const float* xb = x + (size_t)b * N_ * 384;

    for (int mc = 0; mc < N_; mc += MS) {
        const int mlim = (N_ - mc) < MS ? (N_ - mc) : MS;
        __syncthreads();
        for (int i = tid; i < mlim * 96; i += 256) {
            const int mm = i / 96, c4 = i - mm * 96;
            ((float4*)(xs + mm * 384))[c4] =
                ((const float4*)(xb + (size_t)(mc + mm) * 384))[c4];
        }
        for (int i = tid; i < 2 * MS * 8; i += 256) {
            const int k = i >> 7, mm = (i >> 3) & 15, nn = i & 7;
            const int ng = n_base + nn;
            float wv = 0.f;
            if (mm < mlim && ng < N_)
                wv = cheb[(size_t)(k + 1) * (N_ * N_) + (size_t)(mc + mm) * N_ + ng];
            wls[(k * MS + mm) * 8 + nn] = wv;
        }
        __syncthreads();
        for (int mm = 0; mm < mlim; ++mm) {
            const float w1 = wls[mm * 8 + nloc];
            const float w2 = wls[(MS + mm) * 8 + nloc];
            const float* xr = xs + mm * 384 + (cg << 2);
#pragma unroll
            for (int seg = 0; seg < 3; ++seg) {
                const float4 v = *(const float4*)(xr + seg * 128);
                a1[seg*4+0] = fmaf(w1, v.x, a1[seg*4+0]);
                a1[seg*4+1] = fmaf(w1, v.y, a1[seg*4+1]);
                a1[seg*4+2] = fmaf(w1, v.z, a1[seg*4+2]);
                a1[seg*4+3] = fmaf(w1, v.w, a1[seg*4+3]);
                a2[seg*4+0] = fmaf(w2, v.x, a2[seg*4+0]);
                a2[seg*4+1] = fmaf(w2, v.y, a2[seg*4+1]);
                a2[seg*4+2] = fmaf(w2, v.z, a2[seg*4+2]);
                a2[seg*4+3] = fmaf(w2, v.w, a2[seg*4+3]);
            }
        }
    }
    __syncthreads();
#pragma unroll
    for (int seg = 0; seg < 3; ++seg) {
#pragma unroll
        for (int jj = 0; jj < 4; ++jj) {
            const int c = seg * 128 + (cg << 2) + jj;
            const int f = c / 24, t = c - f * 24;
            xc[(nloc * 24 + t) * 16 + f]        = a1[seg * 4 + jj];
            xc[((BN + nloc) * 24 + t) * 16 + f] = a2[seg * 4 + jj];
        }
    }
    __syncthreads();

    __hip_bfloat16* gcn = (__hip_bfloat16*)Y;
    {
        const int c2 = tid & 63;
        const int pg = tid >> 6;
        float th0r[16], th1r[16], th2r[16];
#pragma unroll
        for (int f = 0; f < 16; ++f) {
            th0r[f] = theta[f * 64 + c2];
            th1r[f] = theta[(16 + f) * 64 + c2];
            th2r[f] = theta[(32 + f) * 64 + c2];
        }
        for (int i = 0; i < 48; ++i) {
            const int p  = pg + 4 * i;
            const int nl = p / 24, t = p - nl * 24;
            const int ng = n_base + nl;
            float o = 0.f;
            if (ng < N_) {
                const float* xg = x + ((size_t)b * N_ + ng) * 384 + t;
                const float* x1 = xc + (nl * 24 + t) * 16;
                const float* x2 = xc + ((BN + nl) * 24 + t) * 16;
#pragma unroll
                for (int f = 0; f < 16; ++f)
                    o = fmaf(xg[f * 24], th0r[f], o);
#pragma unroll
                for (int f = 0; f < 16; ++f)
                    o = fmaf(x1[f], th1r[f], fmaf(x2[f], th2r[f], o));
            }
            o = fmaxf(o, 0.f);
            gcn[(nl * 26 + t + 1) * 66 + c2] = __float2bfloat16(o);
            if (t == 0)  gcn[(nl * 26) * 66 + c2]      = __float2bfloat16(0.f);
            if (t == 23) gcn[(nl * 26 + 25) * 66 + c2] = __float2bfloat16(0.f);
        }
    }

    const int nl3 = tid / 24, t3 = tid - nl3 * 24;
    const int ng3 = n_base + nl3;
    const bool act = (tid < 192) && (ng3 < N_);
    float acc[64];
#pragma unroll
    for (int co = 0; co < 64; ++co) acc[co] = misc[co] + misc[64 + co];
    if (act) {
        const float* xg = x + ((size_t)b * N_ + ng3) * 384 + t3;
#pragma unroll
        for (int f = 0; f < 16; ++f) {
            const float xv = xg[f * 24];
            const float* rp = rwl + f * 64;
#pragma unroll
            for (int co = 0; co < 64; ++co) acc[co] = fmaf(xv, rp[co], acc[co]);
        }
    }
    float* twl = xc;
#pragma unroll
    for (int half = 0; half < 2; ++half) {
        __syncthreads();
        for (int i = tid; i < 6144; i += 256)
            twl[i] = tw[((half * 32) + (i & 31)) * 192 + ((i >> 5) & 63) * 3 + (i >> 11)];
        __syncthreads();
        if (act) {
            const __hip_bfloat16* g0 = gcn + (nl3 * 26 + t3) * 66;
#pragma unroll
            for (int dt = 0; dt < 3; ++dt) {
                const __hip_bfloat16* grow = g0 + dt * 66;
                for (int ci = 0; ci < 64; ++ci) {
                    const float g = __bfloat162float(grow[ci]);
                    const float* twp = twl + (dt * 64 + ci) * 32;
#pragma unroll
                    for (int j = 0; j < 32; ++j)
                        acc[half * 32 + j] = fmaf(g, twp[j], acc[half * 32 + j]);
                }
            }
        }
    }
    if (act) {
        float mu = 0.f;
#pragma unroll
        for (int co = 0; co < 64; ++co) { acc[co] = fmaxf(acc[co], 0.f); mu += acc[co]; }
        mu *= (1.f / 64.f);
        float var = 0.f;
#pragma unroll
        for (int co = 0; co < 64; ++co) { const float d = acc[co] - mu; var = fmaf(d, d, var); }
        var *= (1.f / 64.f);
        const float rs = rsqrtf(var + 1e-5f);
        float* op = out + ((size_t)b * N_ + ng3) * (64 * 24) + t3;
#pragma unroll
        for (int co = 0; co < 64; ++co) {
            const float yl = (acc[co] - mu) * rs * misc[128 + co] + misc[192 + co];
            op[(size_t)co * 24] = yl;
        }
    }
}

extern "C" void kernel_launch(void* const* d_in, const int* in_sizes, int n_in,
                              void* d_out, int out_size, void* d_ws, size_t ws_size,
                              hipStream_t stream) {
    (void)out_size;
    const float *px = nullptr, *pcheb = nullptr, *pth = nullptr,
                *ptw = nullptr, *prw = nullptr;
    const float* p64[4] = {nullptr, nullptr, nullptr, nullptr};
    int n64 = 0;
    for (int i = 0; i < n_in; ++i) {
        const float* p = (const float*)d_in[i];
        switch (in_sizes[i]) {
            case 11059200: px    = p; break;
            case 2430000:  pcheb = p; break;
            case 3072:     pth   = p; break;
            case 12288:    ptw   = p; break;
            case 1024:     prw   = p; break;
            case 64:       if (n64 < 4) p64[n64] = p; ++n64; break;
            default: break;
        }
    }
    if (!px || !pcheb || !pth || !ptw || !prw || n64 != 4) {
        px    = (const float*)d_in[0]; pcheb = (const float*)d_in[1];
        pth   = (const float*)d_in[2]; ptw   = (const float*)d_in[3];
        p64[0] = (const float*)d_in[4]; prw  = (const float*)d_in[5];
        p64[1] = (const float*)d_in[6]; p64[2] = (const float*)d_in[7];
        p64[3] = (const float*)d_in[8];
    }
    float* out = (float*)d_out;

    if (ws_size >= (size_t)WS_NEED) {
        unsigned char* ws = (unsigned char*)d_ws;
        __hip_bfloat16* xT    = (__hip_bfloat16*)(ws + OFF_XT);
        __hip_bfloat16* chebT = (__hip_bfloat16*)(ws + OFF_CT);
        __hip_bfloat16* xcb   = (__hip_bfloat16*)(ws + OFF_XC);
        __hip_bfloat16* thT   = (__hip_bfloat16*)(ws + OFF_TH);
        __hip_bfloat16* twB   = (__hip_bfloat16*)(ws + OFF_TW);

        k0_all <<<2761,             256, 0, stream>>>(px, pcheb, ptw, prw, pth,
                                                      xT, chebT, thT, twB);
        k1_mfma<<<960,              512, 0, stream>>>(xT, chebT, xcb);
        k2_mfma<<<dim3(NTILES, B_), 384, 0, stream>>>(px, xcb, thT, twB,
                                                      p64[0], p64[1], p64[2], p64[3], out);
    } else {
        astgcn_fused<<<dim3(NTILES, B_), 256, 0, stream>>>(px, pcheb, pth, ptw,
                                                           p64[0], prw, p64[1],
                                                           p64[2], p64[3], out);
    }
}